// Round 4
// baseline (620.029 us; speedup 1.0000x reference)
//
#include <hip/hip_runtime.h>
#include <hip/hip_bf16.h>
#include <stdint.h>

#define D_DIM 12544
#define NROIS 8192
#define NCOLS 168        // valid output cols: 32+124+3+7+2
#define NCPAD 176        // padded cols in Wp (cols 168..175 are zeros)
#define NT 11
#define SPLIT 8
#define KSPLIT (D_DIM / SPLIT)   // 1568
#define BK 32
#define KITERS (KSPLIT / BK)     // 49
#define BM 64

// LDS layout (bytes): X tile 64 rows x 32 bf16 (64B) padded to 72B -> 2-way banks
//                     W tile 192 cols x 32 bf16 (64B) padded to 80B -> 2-way banks
#define XROW_B 72
#define WCOL_B 80
#define WL_COLS 192
#define XL_BYTES (BM * XROW_B)            // 4608
#define WL_BYTES (WL_COLS * WCOL_B)       // 15360
#define BUF_BYTES (XL_BYTES + WL_BYTES)   // 19968

typedef __attribute__((ext_vector_type(8))) short short8;   // 8 bf16 (MFMA A/B frag)
typedef __attribute__((ext_vector_type(4))) float floatx4;  // MFMA C/D frag

__device__ __forceinline__ uint32_t pk_bf16(float a, float b) {
    uint32_t ua = __float_as_uint(a);
    uint32_t ub = __float_as_uint(b);
    ua = (ua + 0x7FFFu + ((ua >> 16) & 1u)) >> 16;
    ub = (ub + 0x7FFFu + ((ub >> 16) & 1u)) >> 16;
    return ua | (ub << 16);
}

// ---------------- pack W (5 heads) -> Wp[NCPAD][D_DIM] bf16, K-major --------
__global__ __launch_bounds__(256) void pack_w(
        const float* __restrict__ Wc, const float* __restrict__ Wr,
        const float* __restrict__ Wf, const float* __restrict__ Wco,
        const float* __restrict__ Wm, uint16_t* __restrict__ Wp) {
    __shared__ float tile[64][33];
    int k0 = blockIdx.x * 64;
    int c0 = blockIdx.y * 32;
    int t  = threadIdx.x;

    int rc = t & 31;        // read col within tile
    int rk = t >> 5;        // 0..7
#pragma unroll
    for (int rr = 0; rr < 8; ++rr) {
        int k = rr * 8 + rk;
        int kk = k0 + k;
        int c = c0 + rc;
        float v = 0.f;
        if (c < 32)       v = Wc[(size_t)kk * 32  + c];
        else if (c < 156) v = Wr[(size_t)kk * 124 + (c - 32)];
        else if (c < 159) v = Wf[(size_t)kk * 3   + (c - 156)];
        else if (c < 166) v = Wco[(size_t)kk * 7  + (c - 159)];
        else if (c < 168) v = Wm[(size_t)kk * 2   + (c - 166)];
        tile[k][rc] = v;
    }
    __syncthreads();

    int wc = t >> 3;        // 0..31 write col
    int wk = t & 7;         // k-chunk (8 bf16 = 16 B)
    int c  = c0 + wc;
    if (c < NCPAD) {
        uint32_t o[4];
#pragma unroll
        for (int j = 0; j < 4; ++j)
            o[j] = pk_bf16(tile[wk * 8 + 2 * j][wc], tile[wk * 8 + 2 * j + 1][wc]);
        uint4 v = make_uint4(o[0], o[1], o[2], o[3]);
        *(uint4*)(Wp + (size_t)c * D_DIM + k0 + wk * 8) = v;
    }
}

// ---------------- split-K GEMM, LDS-staged, depth-2 reg prefetch ------------
__global__ __launch_bounds__(256, 4) void gemm_split(const float* __restrict__ X,
                                                     const uint16_t* __restrict__ Wp,
                                                     uint16_t* __restrict__ parts) {
    __shared__ __attribute__((aligned(16))) char lds[2 * BUF_BYTES];

    int b     = blockIdx.x;       // 0..1023
    int split = b & 7;            // one split per XCD (round-robin): W slice L2-resident
    int rb    = b >> 3;           // 0..127
    int row0  = rb * BM;
    int kbase = split * KSPLIT;

    int t    = threadIdx.x;
    int wave = t >> 6;
    int lane = t & 63;

    // ---- staging roles ----
    int sx_row = t >> 2;          // 0..63
    int sx_kc  = t & 3;           // 16B chunk (8 fp32 -> 8 bf16)
    const float* xg = X + (size_t)(row0 + sx_row) * D_DIM + kbase + sx_kc * 8;

    int sw_col = t >> 2;          // 0..63, rounds add 64/128
    int sw_ch  = t & 3;           // 16B chunk within col's 64B k-row
    int c0g = sw_col       < NCPAD ? sw_col       : NCPAD - 1;
    int c1g = sw_col + 64  < NCPAD ? sw_col + 64  : NCPAD - 1;
    int c2g = sw_col + 128 < NCPAD ? sw_col + 128 : NCPAD - 1;
    const uint16_t* wg0 = Wp + (size_t)c0g * D_DIM + kbase + sw_ch * 8;
    const uint16_t* wg1 = Wp + (size_t)c1g * D_DIM + kbase + sw_ch * 8;
    const uint16_t* wg2 = Wp + (size_t)c2g * D_DIM + kbase + sw_ch * 8;

    int x_st  = sx_row * XROW_B + sx_kc * 16;
    int w_st0 = XL_BYTES + (sw_col)       * WCOL_B + sw_ch * 16;
    int w_st1 = XL_BYTES + (sw_col + 64)  * WCOL_B + sw_ch * 16;
    int w_st2 = XL_BYTES + (sw_col + 128) * WCOL_B + sw_ch * 16;

    // ---- frag roles ----
    int n    = lane & 15;         // X row within wave tile / W col within tile
    int quad = lane >> 4;         // k-chunk
    int xf_off = (wave * 16 + n) * XROW_B + quad * 16;
    int wf_off = XL_BYTES + n * WCOL_B + quad * 16;   // + tt*16*WCOL_B

    floatx4 acc[NT];
#pragma unroll
    for (int tt = 0; tt < NT; ++tt) acc[tt] = (floatx4)0.f;

    // two register staging sets, ping-ponged
    float4 ax0, ax1; short8 aw0, aw1, aw2;
    float4 bx0, bx1; short8 bw0, bw1, bw2;

    auto issueA = [&]() {
        ax0 = *(const float4*)xg; ax1 = *(const float4*)(xg + 4); xg += BK;
        aw0 = *(const short8*)wg0; wg0 += BK;
        aw1 = *(const short8*)wg1; wg1 += BK;
        aw2 = *(const short8*)wg2; wg2 += BK;
    };
    auto issueB = [&]() {
        bx0 = *(const float4*)xg; bx1 = *(const float4*)(xg + 4); xg += BK;
        bw0 = *(const short8*)wg0; wg0 += BK;
        bw1 = *(const short8*)wg1; wg1 += BK;
        bw2 = *(const short8*)wg2; wg2 += BK;
    };
    auto stageA = [&](char* nb) {
        union { uint32_t u[4]; short8 s; } p;
        p.u[0] = pk_bf16(ax0.x, ax0.y); p.u[1] = pk_bf16(ax0.z, ax0.w);
        p.u[2] = pk_bf16(ax1.x, ax1.y); p.u[3] = pk_bf16(ax1.z, ax1.w);
        *(short8*)(nb + x_st)  = p.s;
        *(short8*)(nb + w_st0) = aw0;
        *(short8*)(nb + w_st1) = aw1;
        *(short8*)(nb + w_st2) = aw2;
    };
    auto stageB = [&](char* nb) {
        union { uint32_t u[4]; short8 s; } p;
        p.u[0] = pk_bf16(bx0.x, bx0.y); p.u[1] = pk_bf16(bx0.z, bx0.w);
        p.u[2] = pk_bf16(bx1.x, bx1.y); p.u[3] = pk_bf16(bx1.z, bx1.w);
        *(short8*)(nb + x_st)  = p.s;
        *(short8*)(nb + w_st0) = bw0;
        *(short8*)(nb + w_st1) = bw1;
        *(short8*)(nb + w_st2) = bw2;
    };
    auto compute = [&](const char* cb) {
        short8 xf = *(const short8*)(cb + xf_off);
#pragma unroll
        for (int tt = 0; tt < NT; ++tt) {
            short8 wf = *(const short8*)(cb + wf_off + tt * (16 * WCOL_B));
            acc[tt] = __builtin_amdgcn_mfma_f32_16x16x32_bf16(wf, xf, acc[tt], 0, 0, 0);
        }
    };

    // prologue: G(0)->A, G(1)->B, stage A into buf0 (waits only A's vmcnt)
    issueA();
    issueB();
    stageA(lds);

    for (int it = 0; it < KITERS; it += 2) {
        // ---- body 0: compute buf0, stage B(G(it+1)) -> buf1 ----
        __syncthreads();
        if (it + 2 < KITERS) issueA();          // G(it+2): in flight ~2 iters
        compute(lds);
        if (it + 1 < KITERS) stageB(lds + BUF_BYTES);  // waits B: issued 1.5-2 iters ago

        // ---- body 1: compute buf1, stage A(G(it+2)) -> buf0 ----
        __syncthreads();
        if (it + 1 < KITERS) {
            if (it + 3 < KITERS) issueB();      // G(it+3)
            compute(lds + BUF_BYTES);
            if (it + 2 < KITERS) stageA(lds);
        }
    }

    // ---- epilogue: D layout col(n)=X row, out-col = quad*4+reg (+16*tt) ----
    uint16_t* pb = parts + ((size_t)split * NROIS + row0 + wave * 16 + n) * NCOLS;
#pragma unroll
    for (int tt = 0; tt < NT; ++tt) {
        int col0 = tt * 16 + quad * 4;
        if (col0 + 3 < NCOLS) {
            uint32_t lo = pk_bf16(acc[tt].x, acc[tt].y);
            uint32_t hi = pk_bf16(acc[tt].z, acc[tt].w);
            uint2 v = make_uint2(lo, hi);
            *(uint2*)(pb + col0) = v;
        }
    }
}

// ---------------- reduce partials (bf16) + bias, scatter to 5 heads ---------
__global__ void reduce_out(const uint16_t* __restrict__ parts,
                           const float* __restrict__ bc, const float* __restrict__ br,
                           const float* __restrict__ bf, const float* __restrict__ bco,
                           const float* __restrict__ bm, float* __restrict__ out) {
    int r = blockIdx.x;
    int c = threadIdx.x;
    if (c >= NCOLS) return;
    const size_t S = (size_t)NROIS * NCOLS;
    size_t off = (size_t)r * NCOLS + c;
    float v = 0.f;
#pragma unroll
    for (int s = 0; s < SPLIT; ++s)
        v += __uint_as_float((uint32_t)parts[off + (size_t)s * S] << 16);
    float bias; size_t oidx;
    if (c < 32)       { bias = bc[c];        oidx = (size_t)r * 32  + c; }
    else if (c < 156) { bias = br[c - 32];   oidx = 262144u  + (size_t)r * 124 + (c - 32); }
    else if (c < 159) { bias = bf[c - 156];  oidx = 1277952u + (size_t)r * 3   + (c - 156); }
    else if (c < 166) { bias = bco[c - 159]; oidx = 1302528u + (size_t)r * 7   + (c - 159); }
    else              { bias = bm[c - 166];  oidx = 1359872u + (size_t)r * 2   + (c - 166); }
    out[oidx] = v + bias;
}

extern "C" void kernel_launch(void* const* d_in, const int* in_sizes, int n_in,
                              void* d_out, int out_size, void* d_ws, size_t ws_size,
                              hipStream_t stream) {
    const float* X   = (const float*)d_in[0];
    const float* Wc  = (const float*)d_in[1];
    const float* bc  = (const float*)d_in[2];
    const float* Wr  = (const float*)d_in[3];
    const float* br  = (const float*)d_in[4];
    const float* Wf  = (const float*)d_in[5];
    const float* bfa = (const float*)d_in[6];
    const float* Wco = (const float*)d_in[7];
    const float* bco = (const float*)d_in[8];
    const float* Wm  = (const float*)d_in[9];
    const float* bm  = (const float*)d_in[10];

    uint16_t* Wp    = (uint16_t*)d_ws;                                      // 4,415,488 B
    uint16_t* parts = (uint16_t*)((char*)d_ws + (size_t)NCPAD * D_DIM * 2); // 22,020,096 B (bf16)
    float* out = (float*)d_out;

    pack_w<<<dim3(D_DIM / 64, 6), 256, 0, stream>>>(Wc, Wr, Wf, Wco, Wm, Wp);
    gemm_split<<<1024, 256, 0, stream>>>(X, Wp, parts);
    reduce_out<<<NROIS, 192, 0, stream>>>(parts, bc, br, bfa, bco, bm, out);
}